// Round 8
// baseline (59.603 us; speedup 1.0000x reference)
//
#include <hip/hip_runtime.h>

#define N_SEG 256
#define HIDDEN 512
#define NB 2048          // 8 blocks per CU exactly; one residency round
#define NB_SHIFT 11
#define MAXROWS 96       // >= ceil(n/NB); n=100000 -> 49
#define NEG_INF (-__builtin_inff())

// Block b owns rows [n*b/NB, n*(b+1)/NB) — pure arithmetic, no searches, so the
// first x prefetch issues at cycle 0. The block's ~49 batch values are loaded
// to LDS in one coalesced round-trip (hidden under that prefetch), the range is
// split into segment slices locally, and each slice is streamed with 4
// interleaved waves (one sequential ~8KB-burst stream), online softmax + LDS
// merge, one partial (m,d,acc[512]) at slot = slice start row (global index).
__global__ __launch_bounds__(256) void fused_kernel(
    const float* __restrict__ x, const float* __restrict__ W,
    const int* __restrict__ batch,
    float* __restrict__ pacc, float* __restrict__ pm, float* __restrict__ pd,
    int n) {
    int b = blockIdx.x;
    int r0 = (int)(((long long)n * b) >> NB_SHIFT);
    int r1 = (int)(((long long)n * (b + 1)) >> NB_SHIFT);
    int len = r1 - r0;
    int t = threadIdx.x, lane = t & 63, w = t >> 6;

    // issue first owned row's load immediately
    float4 pa0, pa1;
    if (r0 + w < r1) {
        const float* xr = x + (size_t)(r0 + w) * HIDDEN + lane * 8;
        pa0 = *(const float4*)xr; pa1 = *(const float4*)(xr + 4);
    }
    float4 w0 = *(const float4*)(W + lane * 8);
    float4 w1 = *(const float4*)(W + lane * 8 + 4);

    __shared__ int sbatch[MAXROWS];
    if (t < len) sbatch[t] = batch[r0 + t];
    __syncthreads();

    __shared__ float sm[4], sd[4];
    __shared__ float sacc[4][HIDDEN];  // 8 KB

    int q0 = 0;
    while (q0 < len) {                 // block-uniform slice loop
        int seg = sbatch[q0];
        int q1 = q0 + 1;
        while (q1 < len && sbatch[q1] == seg) ++q1;
        int st = r0 + q0, en = r0 + q1;

        float m = NEG_INF, d = 0.0f;
        float acc[8] = {0, 0, 0, 0, 0, 0, 0, 0};
        int i = st + w;
        bool have = i < en;            // wave-uniform
        float4 a0, a1;
        if (have) {
            if (q0 == 0) { a0 = pa0; a1 = pa1; }   // uniform: st==r0 only when q0==0
            else {
                const float* xr = x + (size_t)i * HIDDEN + lane * 8;
                a0 = *(const float4*)xr; a1 = *(const float4*)(xr + 4);
            }
        }
        while (have) {
            int inext = i + 4;
            bool hnext = inext < en;
            float4 b0, b1;
            if (hnext) {               // depth-1 prefetch of next owned row
                const float* xr = x + (size_t)inext * HIDDEN + lane * 8;
                b0 = *(const float4*)xr; b1 = *(const float4*)(xr + 4);
            }
            float g = a0.x * w0.x + a0.y * w0.y + a0.z * w0.z + a0.w * w0.w
                    + a1.x * w1.x + a1.y * w1.y + a1.z * w1.z + a1.w * w1.w;
            #pragma unroll
            for (int off = 32; off; off >>= 1) g += __shfl_xor(g, off, 64);
            float mn = fmaxf(m, g);
            float scale = __expf(m - mn);  // 0 on first row (m=-inf)
            float p = __expf(g - mn);
            d = d * scale + p;
            acc[0] = acc[0] * scale + p * a0.x;  acc[1] = acc[1] * scale + p * a0.y;
            acc[2] = acc[2] * scale + p * a0.z;  acc[3] = acc[3] * scale + p * a0.w;
            acc[4] = acc[4] * scale + p * a1.x;  acc[5] = acc[5] * scale + p * a1.y;
            acc[6] = acc[6] * scale + p * a1.z;  acc[7] = acc[7] * scale + p * a1.w;
            m = mn;
            a0 = b0; a1 = b1; i = inext; have = hnext;
        }

        // block-level softmax merge of the 4 waves via LDS
        if (lane == 0) sm[w] = m;
        __syncthreads();
        float M = fmaxf(fmaxf(sm[0], sm[1]), fmaxf(sm[2], sm[3]));  // wave 0 nonempty
        float scale = (m == NEG_INF) ? 0.0f : __expf(m - M);        // short-slice waves
        if (lane == 0) sd[w] = d * scale;
        #pragma unroll
        for (int j = 0; j < 8; ++j) sacc[w][lane * 8 + j] = acc[j] * scale;
        __syncthreads();
        if (t == 0) { pm[st] = M; pd[st] = sd[0] + sd[1] + sd[2] + sd[3]; }
        for (int j = t; j < HIDDEN; j += 256)
            pacc[(size_t)st * HIDDEN + j] = sacc[0][j] + sacc[1][j] + sacc[2][j] + sacc[3][j];
        __syncthreads();               // protect sm/sacc reuse in next slice
        q0 = q1;
    }
}

__device__ __forceinline__ int b_of(int r, int n) {
    int b = (int)(((long long)r << NB_SHIFT) / n);
    while ((int)(((long long)n * (b + 1)) >> NB_SHIFT) <= r) ++b;
    while ((int)(((long long)n * b) >> NB_SHIFT) > r) --b;
    return b;
}

// One block per segment: 2 binary searches (batch is L2-warm after fused),
// enumerate overlapping blocks arithmetically; block b's partial for segment s
// sits at slot max(ss, r0(b)). Softmax-merge ~10 partials, write 512 cols.
__global__ __launch_bounds__(256) void merge_kernel(
    const int* __restrict__ batch, const float* __restrict__ pacc,
    const float* __restrict__ pm, const float* __restrict__ pd,
    float* __restrict__ out, int n) {
    int s = blockIdx.x, t = threadIdx.x;
    int lo = 0, hi = n;
    while (lo < hi) { int mid = (lo + hi) >> 1; if (batch[mid] < s) lo = mid + 1; else hi = mid; }
    int ss = lo; hi = n;
    while (lo < hi) { int mid = (lo + hi) >> 1; if (batch[mid] < s + 1) lo = mid + 1; else hi = mid; }
    int se = lo;
    if (ss >= se) { out[s * HIDDEN + t] = 0.0f; out[s * HIDDEN + 256 + t] = 0.0f; return; }

    int blo = b_of(ss, n), bhi = b_of(se - 1, n);
    float M = NEG_INF;
    for (int b = blo; b <= bhi; ++b) {
        int r0b = (int)(((long long)n * b) >> NB_SHIFT);
        int slot = ss > r0b ? ss : r0b;
        M = fmaxf(M, pm[slot]);
    }
    float D = 0.0f;
    for (int b = blo; b <= bhi; ++b) {
        int r0b = (int)(((long long)n * b) >> NB_SHIFT);
        int slot = ss > r0b ? ss : r0b;
        D += pd[slot] * __expf(pm[slot] - M);
    }
    float invD = 1.0f / (D + 1e-16f);
    float num0 = 0.0f, num1 = 0.0f;
    for (int b = blo; b <= bhi; ++b) {
        int r0b = (int)(((long long)n * b) >> NB_SHIFT);
        int slot = ss > r0b ? ss : r0b;
        float wt = __expf(pm[slot] - M);
        num0 += pacc[(size_t)slot * HIDDEN + t] * wt;
        num1 += pacc[(size_t)slot * HIDDEN + 256 + t] * wt;
    }
    out[s * HIDDEN + t] = num0 * invD;
    out[s * HIDDEN + 256 + t] = num1 * invD;
}

extern "C" void kernel_launch(void* const* d_in, const int* in_sizes, int n_in,
                              void* d_out, int out_size, void* d_ws, size_t ws_size,
                              hipStream_t stream) {
    const float* x     = (const float*)d_in[0];
    const int*   batch = (const int*)d_in[1];
    const float* W     = (const float*)d_in[2];
    int n = in_sizes[1];
    float* out = (float*)d_out;

    // ws: pacc[n*512] (16B-aligned first) | pm[n] | pd[n]  (~206 MB)
    float* pacc = (float*)d_ws;
    float* pm   = pacc + (size_t)n * HIDDEN;
    float* pd   = pm + n;

    fused_kernel<<<NB, 256, 0, stream>>>(x, W, batch, pacc, pm, pd, n);
    merge_kernel<<<N_SEG, 256, 0, stream>>>(batch, pacc, pm, pd, out, n);
}